// Round 6
// baseline (172.981 us; speedup 1.0000x reference)
//
#include <hip/hip_runtime.h>
#include <math.h>

#define IMG_H 4096
#define IMG_W 4096
#define RPT 8                 // rows per wave
#define WPR (IMG_W / 256)     // waves per row strip: each wave spans 256 cols

typedef float floatx4 __attribute__((ext_vector_type(4)));

// Quantize angle exactly like the reference float32 path; pick the two
// neighbors branchlessly; emit img if local-max & interior.
__device__ __forceinline__ float nms_px(float t, bool interior,
                                        float uL, float uC, float uR,
                                        float cL, float cC, float cR,
                                        float dL, float dC, float dR) {
    float deg = t * 57.29577951308232f;        // float32(180/pi)
    deg = (deg < 0.0f) ? deg + 180.0f : deg;
    float q = rintf(deg / 45.0f) * 45.0f;      // IEEE div + round-half-even
    const bool is0  = (q == 0.0f) || (q == 180.0f);
    const bool is45 = (q == 45.0f);
    const bool is90 = (q == 90.0f);
    const float a = is0 ? cR : (is45 ? dR : (is90 ? dC : dL));
    const float b = is0 ? cL : (is45 ? uL : (is90 ? uC : uR));
    return ((cC >= a) && (cC >= b) && interior) ? cC : 0.0f;
}

// One wave = 256 contiguous cols x RPT rows. ALL loads for the strip (10 img
// rows + 10 edge scalars + 8 theta rows) are issued up front -> ~20 VMEM in
// flight per wave, one latency exposure per strip instead of one per row
// (r1-r5 were latency-bound at prefetch-distance <=1: VALUBusy ~25%).
// Horizontal neighbors via wave shuffles; lanes 0/63 fetch boundary columns.
__global__ __launch_bounds__(256) void nms_kernel(const float* __restrict__ img,
                                                  const float* __restrict__ theta,
                                                  float* __restrict__ out) {
    const int gtid = blockIdx.x * 256 + threadIdx.x;
    const int wave = gtid >> 6;
    const int lane = gtid & 63;
    const int g  = wave / WPR;          // row-group index
    const int wc = (wave % WPR) << 8;   // wave's first column
    const int y4 = wc + (lane << 2);    // this lane's 4-px chunk
    const int x0 = g * RPT;

    const bool is_l = (lane == 0);
    const bool is_r = (lane == 63);
    const bool edge_lane = is_l || is_r;
    const int ye = is_l ? (wc > 0 ? wc - 1 : 0)
                        : (wc + 256 < IMG_W ? wc + 256 : IMG_W - 1);

    const bool c0_int = (y4 > 0);
    const bool c3_int = (y4 + 4 < IMG_W);

    floatx4 r[RPT + 2];
    float   e[RPT + 2];
    floatx4 th[RPT];

    // ---- issue every load for the strip back-to-back ----
    #pragma unroll
    for (int i = 0; i < RPT + 2; ++i) {
        int x = x0 - 1 + i;
        x = (x < 0) ? 0 : ((x > IMG_H - 1) ? IMG_H - 1 : x);  // clamped; borders output 0
        const float* __restrict__ pr = img + (size_t)x * IMG_W;
        r[i] = *(const floatx4*)(pr + y4);
        e[i] = 0.0f;
        if (edge_lane) e[i] = pr[ye];   // 2 active lanes, 2 cache lines
    }
    #pragma unroll
    for (int i = 0; i < RPT; ++i) {
        th[i] = *(const floatx4*)(theta + (size_t)(x0 + i) * IMG_W + y4);
    }

    // ---- compute + store ----
    #pragma unroll
    for (int i = 0; i < RPT; ++i) {
        const int x = x0 + i;
        const floatx4 u = r[i],     c = r[i + 1], d = r[i + 2];
        const float  ue = e[i],    ce = e[i + 1], de = e[i + 2];
        const floatx4 t = th[i];

        const float uLs = __shfl_up(u.w, 1, 64), uRs = __shfl_down(u.x, 1, 64);
        const float cLs = __shfl_up(c.w, 1, 64), cRs = __shfl_down(c.x, 1, 64);
        const float dLs = __shfl_up(d.w, 1, 64), dRs = __shfl_down(d.x, 1, 64);
        const float uL = is_l ? ue : uLs, uR = is_r ? ue : uRs;
        const float cL = is_l ? ce : cLs, cR = is_r ? ce : cRs;
        const float dL = is_l ? de : dLs, dR = is_r ? de : dRs;

        const bool row_int = (x > 0) && (x < IMG_H - 1);

        floatx4 o;
        o.x = nms_px(t.x, row_int && c0_int, uL,  u.x, u.y,  cL,  c.x, c.y,  dL,  d.x, d.y);
        o.y = nms_px(t.y, row_int,           u.x, u.y, u.z,  c.x, c.y, c.z,  d.x, d.y, d.z);
        o.z = nms_px(t.z, row_int,           u.y, u.z, u.w,  c.y, c.z, c.w,  d.y, d.z, d.w);
        o.w = nms_px(t.w, row_int && c3_int, u.z, u.w, uR,   c.z, c.w, cR,   d.z, d.w, dR);

        floatx4* po = (floatx4*)(out + (size_t)x * IMG_W + y4);
        __builtin_nontemporal_store(o, po);
    }
}

extern "C" void kernel_launch(void* const* d_in, const int* in_sizes, int n_in,
                              void* d_out, int out_size, void* d_ws, size_t ws_size,
                              hipStream_t stream) {
    const float* img   = (const float*)d_in[0];
    const float* theta = (const float*)d_in[1];
    float* out = (float*)d_out;

    const int total_threads = (IMG_H / RPT) * WPR * 64;  // 512 * 16 * 64
    const int block = 256;
    const int grid = total_threads / block;               // 2048
    nms_kernel<<<grid, block, 0, stream>>>(img, theta, out);
}

// Round 7
// 168.631 us; speedup vs baseline: 1.0258x; 1.0258x over previous
//
#include <hip/hip_runtime.h>
#include <math.h>

#define IMG_H 4096
#define IMG_W 4096
#define RPT 8                 // rows per wave
#define WPR (IMG_W / 256)     // waves per row strip: each wave spans 256 cols

typedef float floatx4 __attribute__((ext_vector_type(4)));

// Branch selection equivalent (verified bit-exact by boundary ulp-analysis) to:
//   q = rintf(deg/45.f)*45.f;  q==180 -> 0;  chain-compare 0/45/90/else.
// Windows (all boundary constants exactly representable; ties at exact .5
// quotients resolve half-even exactly as the inclusivity below encodes):
//   is0 : deg in [-22.5, 22.5] u [157.5, 202.5]
//   is45: deg in (22.5, 67.5)
//   is90: deg in [67.5, 112.5]
//   else: 135 branch (covers negatives < -22.5, >202.5 windows, NaN)
__device__ __forceinline__ float nms_px(float t, bool interior,
                                        float uL, float uC, float uR,
                                        float cL, float cC, float cR,
                                        float dL, float dC, float dR) {
    float deg = t * 57.29577951308232f;        // float32(180/pi)
    deg = (deg < 0.0f) ? deg + 180.0f : deg;   // same fp32 add as reference
    const bool is0  = (deg >= -22.5f && deg <= 22.5f) || (deg >= 157.5f && deg <= 202.5f);
    const bool is45 = (deg >  22.5f) && (deg <  67.5f);
    const bool is90 = (deg >= 67.5f) && (deg <= 112.5f);
    const float a = is0 ? cR : (is45 ? dR : (is90 ? dC : dL));
    const float b = is0 ? cL : (is45 ? uL : (is90 ? uC : uR));
    return ((cC >= a) && (cC >= b) && interior) ? cC : 0.0f;
}

// One wave = 256 contiguous cols x RPT rows; all strip loads issued up front.
// __launch_bounds__(256,2) raises the VGPR cap to ~256 so the compiler can
// actually keep the load arrays live (r6: default cap forced VGPR=40 and
// re-serialized the loads — MLP never happened).
// Block->work mapping keeps vertically adjacent strips on one XCD (blk%8).
__global__ __launch_bounds__(256, 2) void nms_kernel(const float* __restrict__ img,
                                                     const float* __restrict__ theta,
                                                     float* __restrict__ out) {
    // XCD-aware remap: 2048 blocks, blk%8 = XCD -> 8 horizontal bands of 512 rows.
    const int xcd  = blockIdx.x & 7;
    const int slot = blockIdx.x >> 3;          // 0..255 within band
    const int g    = xcd * 64 + (slot >> 2);   // row-group (64 groups of 8 rows per band)
    const int seg  = (slot & 3) * 4 + (threadIdx.x >> 6);  // col segment 0..15
    const int lane = threadIdx.x & 63;

    const int wc = seg << 8;            // wave's first column
    const int y4 = wc + (lane << 2);    // this lane's 4-px chunk
    const int x0 = g * RPT;

    const bool is_l = (lane == 0);
    const bool is_r = (lane == 63);
    const bool edge_lane = is_l || is_r;
    const int ye = is_l ? (wc > 0 ? wc - 1 : 0)
                        : (wc + 256 < IMG_W ? wc + 256 : IMG_W - 1);

    const bool c0_int = (y4 > 0);
    const bool c3_int = (y4 + 4 < IMG_W);

    floatx4 r[RPT + 2];
    float   e[RPT + 2];
    floatx4 th[RPT];

    // ---- issue every load for the strip back-to-back (~28 VMEM in flight) ----
    #pragma unroll
    for (int i = 0; i < RPT + 2; ++i) {
        int x = x0 - 1 + i;
        x = (x < 0) ? 0 : ((x > IMG_H - 1) ? IMG_H - 1 : x);
        const float* __restrict__ pr = img + (size_t)x * IMG_W;
        r[i] = *(const floatx4*)(pr + y4);
        e[i] = 0.0f;
        if (edge_lane) e[i] = pr[ye];
    }
    #pragma unroll
    for (int i = 0; i < RPT; ++i) {
        const float* tp = theta + (size_t)(x0 + i) * IMG_W + y4;
        th[i] = __builtin_nontemporal_load((const floatx4*)tp);
    }

    // ---- compute + store ----
    #pragma unroll
    for (int i = 0; i < RPT; ++i) {
        const int x = x0 + i;
        const floatx4 u = r[i],   c = r[i + 1], d = r[i + 2];
        const float  ue = e[i],  ce = e[i + 1], de = e[i + 2];
        const floatx4 t = th[i];

        const float uLs = __shfl_up(u.w, 1, 64), uRs = __shfl_down(u.x, 1, 64);
        const float cLs = __shfl_up(c.w, 1, 64), cRs = __shfl_down(c.x, 1, 64);
        const float dLs = __shfl_up(d.w, 1, 64), dRs = __shfl_down(d.x, 1, 64);
        const float uL = is_l ? ue : uLs, uR = is_r ? ue : uRs;
        const float cL = is_l ? ce : cLs, cR = is_r ? ce : cRs;
        const float dL = is_l ? de : dLs, dR = is_r ? de : dRs;

        const bool row_int = (x > 0) && (x < IMG_H - 1);

        floatx4 o;
        o.x = nms_px(t.x, row_int && c0_int, uL,  u.x, u.y,  cL,  c.x, c.y,  dL,  d.x, d.y);
        o.y = nms_px(t.y, row_int,           u.x, u.y, u.z,  c.x, c.y, c.z,  d.x, d.y, d.z);
        o.z = nms_px(t.z, row_int,           u.y, u.z, u.w,  c.y, c.z, c.w,  d.y, d.z, d.w);
        o.w = nms_px(t.w, row_int && c3_int, u.z, u.w, uR,   c.z, c.w, cR,   d.z, d.w, dR);

        floatx4* po = (floatx4*)(out + (size_t)x * IMG_W + y4);
        __builtin_nontemporal_store(o, po);
    }
}

extern "C" void kernel_launch(void* const* d_in, const int* in_sizes, int n_in,
                              void* d_out, int out_size, void* d_ws, size_t ws_size,
                              hipStream_t stream) {
    const float* img   = (const float*)d_in[0];
    const float* theta = (const float*)d_in[1];
    float* out = (float*)d_out;

    const int total_threads = (IMG_H / RPT) * WPR * 64;  // 512 * 16 * 64
    const int block = 256;
    const int grid = total_threads / block;               // 2048
    nms_kernel<<<grid, block, 0, stream>>>(img, theta, out);
}